// Round 2
// baseline (8333.134 us; speedup 1.0000x reference)
//
#include <hip/hip_runtime.h>
#include <hip/hip_fp16.h>

// GRU: T=2048, B=64, I=H=256.  out = ([T,B,H] f32, initial hx)
//
//  1) cvt_init: f32->f16 weight copies into ws, h_state := hx, write hx tail of d_out.
//  2) gi_gemm:  gi = x @ x2h_w^T + x2h_b via f16 MFMA, stored f16 in ws. (parallel over T)
//  3) gru_rec:  64 WGs (one per batch element) x 256 threads. Thread j owns ALL THREE
//               h2h_w rows for output j (r: j, z: j+256, n: j+512) as 384 register-
//               resident VGPRs (launch_bounds(256,1) -> 512 VGPR cap, no spill <=450).
//               Per step: 384 v_dot2_f32_f16 per thread with h broadcast from LDS,
//               gates computed fully in-thread (no gh LDS round-trip), ONE barrier
//               per step via double-buffered h. gi prefetched 2 steps ahead.

typedef _Float16 half2v __attribute__((ext_vector_type(2)));
typedef _Float16 half8  __attribute__((ext_vector_type(8)));
typedef float    f32x4  __attribute__((ext_vector_type(4)));
typedef unsigned int uint4v __attribute__((ext_vector_type(4)));

#define T_SEQ 2048
#define BATCH 64
#define HDIM  256
#define G3    768   // 3*H

__device__ __forceinline__ half2v u2h(unsigned int u) {
    union { unsigned int u; half2v h; } c; c.u = u; return c.h;
}

__device__ __forceinline__ float fdot2(half2v a, half2v b, float c) {
#if __has_builtin(__builtin_amdgcn_fdot2)
    return __builtin_amdgcn_fdot2(a, b, c, false);
#else
    return c + (float)a[0] * (float)b[0] + (float)a[1] * (float)b[1];
#endif
}

__device__ __forceinline__ float sigmoid_f(float x) {
    return 1.f / (1.f + __expf(-x));
}
__device__ __forceinline__ float tanh_f(float x) {
    // 1 - 2/(e^{2x}+1): saturates correctly for |x| large (no inf/inf NaN)
    float e = __expf(2.f * x);
    return 1.f - 2.f / (e + 1.f);
}

// ---------------------------------------------------------------- cvt_init
__global__ void cvt_init(const float* __restrict__ x2h_w, const float* __restrict__ h2h_w,
                         const float* __restrict__ hx,
                         _Float16* __restrict__ wx16, _Float16* __restrict__ wh16,
                         float* __restrict__ hstate, float* __restrict__ out_tail) {
    int i = blockIdx.x * 256 + threadIdx.x;
    if (i < G3 * HDIM) {
        wx16[i] = (_Float16)x2h_w[i];
        wh16[i] = (_Float16)h2h_w[i];
    }
    if (i < BATCH * HDIM) {
        float v = hx[i];
        hstate[i] = v;
        out_tail[i] = v;   // second output = INITIAL hx
    }
}

// ---------------------------------------------------------------- gi_gemm
// Grid: (nrows/256) WGs of 256 threads (4 waves). Wave handles 64 rows (4 strips of 16).
// mfma_f32_16x16x32_f16: A lane holds A[row=l&15, k=(l>>4)*8+i];
// B lane holds B[k=(l>>4)*8+i, col=l&15]; D lane holds C[row=(l>>4)*4+r, col=l&15].
__global__ __launch_bounds__(256) void gi_gemm(const float* __restrict__ x,
                                               const _Float16* __restrict__ wx,
                                               const float* __restrict__ bx,
                                               _Float16* __restrict__ gi,
                                               int row_base) {
    const int lane  = threadIdx.x & 63;
    const int wave  = threadIdx.x >> 6;
    const int l15   = lane & 15;
    const int kslot = lane >> 4;               // 0..3
    const int row0  = row_base + blockIdx.x * 256 + wave * 64;

    half8 a[4][8];
    #pragma unroll
    for (int s = 0; s < 4; ++s) {
        const float* xr = x + (size_t)(row0 + s * 16 + l15) * HDIM + kslot * 8;
        #pragma unroll
        for (int kt = 0; kt < 8; ++kt) {
            float4 lo = *(const float4*)(xr + kt * 32);
            float4 hi = *(const float4*)(xr + kt * 32 + 4);
            half8 v;
            v[0] = (_Float16)lo.x; v[1] = (_Float16)lo.y; v[2] = (_Float16)lo.z; v[3] = (_Float16)lo.w;
            v[4] = (_Float16)hi.x; v[5] = (_Float16)hi.y; v[6] = (_Float16)hi.z; v[7] = (_Float16)hi.w;
            a[s][kt] = v;
        }
    }

    for (int nt = 0; nt < 48; ++nt) {
        half8 b[8];
        const _Float16* wr = wx + (size_t)(nt * 16 + l15) * HDIM + kslot * 8;
        #pragma unroll
        for (int kt = 0; kt < 8; ++kt) b[kt] = *(const half8*)(wr + kt * 32);
        const int   col  = nt * 16 + l15;
        const float bias = bx[col];
        #pragma unroll
        for (int s = 0; s < 4; ++s) {
            f32x4 acc = {0.f, 0.f, 0.f, 0.f};
            #pragma unroll
            for (int kt = 0; kt < 8; ++kt)
                acc = __builtin_amdgcn_mfma_f32_16x16x32_f16(a[s][kt], b[kt], acc, 0, 0, 0);
            #pragma unroll
            for (int r = 0; r < 4; ++r) {
                int rowl = (row0 - row_base) + s * 16 + kslot * 4 + r;
                gi[(size_t)rowl * G3 + col] = (_Float16)(acc[r] + bias);
            }
        }
    }
}

// ---------------------------------------------------------------- gru_rec
// 64 WGs x 256 threads. Thread j holds h2h_w rows j / j+256 / j+512 in 384 VGPRs.
__global__ __launch_bounds__(256, 1) void gru_rec(const _Float16* __restrict__ gi,
                                                  const _Float16* __restrict__ wh,
                                                  const float* __restrict__ bh,
                                                  const float* __restrict__ hx,
                                                  float* __restrict__ hstate,
                                                  float* __restrict__ out,
                                                  int t_start, int t_len) {
    __shared__ __align__(16) _Float16 hbuf[2][HDIM];

    const int j = threadIdx.x;
    const int b = blockIdx.x;

    // 3 weight rows -> 96 x uint4v = 384 VGPRs, pinned so loads can't sink into loop
    uint4v wr[32], wz[32], wn[32];
    {
        const uint4v* pr = (const uint4v*)(wh + (size_t)j * HDIM);
        const uint4v* pz = (const uint4v*)(wh + (size_t)(j + 256) * HDIM);
        const uint4v* pn = (const uint4v*)(wh + (size_t)(j + 512) * HDIM);
        #pragma unroll
        for (int i = 0; i < 32; ++i) { wr[i] = pr[i]; wz[i] = pz[i]; wn[i] = pn[i]; }
    }
    #pragma unroll
    for (int i = 0; i < 32; ++i)
        asm volatile("" : "+v"(wr[i]), "+v"(wz[i]), "+v"(wn[i]));

    const float br = bh[j];
    const float bz = bh[j + 256];
    const float bn = bh[j + 512];

    float h_old;
    if (t_start == 0) h_old = hx[b * HDIM + j];
    else              h_old = hstate[b * HDIM + j];
    hbuf[0][j] = (_Float16)h_old;
    __syncthreads();

    const _Float16* gib = gi + (size_t)b * G3 + j;
    const size_t STEP = (size_t)BATCH * G3;

    // 2-deep gi prefetch pipeline: sA = step tt, sB = step tt+1
    float grA = (float)gib[0];
    float gzA = (float)gib[256];
    float gnA = (float)gib[512];
    float grB = (float)gib[STEP];
    float gzB = (float)gib[STEP + 256];
    float gnB = (float)gib[STEP + 512];

    int p = 0;
    float* outp = out + ((size_t)t_start * BATCH + b) * HDIM + j;
    const size_t OSTEP = (size_t)BATCH * HDIM;

    for (int tt = 0; tt < t_len; tt += 2) {
        // ---------------- even step (uses A, refills A from tt+2) ----------------
        {
            float cr = grA, cz = gzA, cn = gnA;
            int tp = (tt + 2 < t_len) ? tt + 2 : t_len - 1;
            grA = (float)gib[(size_t)tp * STEP];
            gzA = (float)gib[(size_t)tp * STEP + 256];
            gnA = (float)gib[(size_t)tp * STEP + 512];

            float ar = 0.f, az = 0.f, an = 0.f;
            const uint4v* hp = (const uint4v*)hbuf[p];
            #pragma unroll
            for (int i = 0; i < 32; ++i) {
                uint4v hv = hp[i];
                ar = fdot2(u2h(wr[i][0]), u2h(hv[0]), ar);
                ar = fdot2(u2h(wr[i][1]), u2h(hv[1]), ar);
                ar = fdot2(u2h(wr[i][2]), u2h(hv[2]), ar);
                ar = fdot2(u2h(wr[i][3]), u2h(hv[3]), ar);
                az = fdot2(u2h(wz[i][0]), u2h(hv[0]), az);
                az = fdot2(u2h(wz[i][1]), u2h(hv[1]), az);
                az = fdot2(u2h(wz[i][2]), u2h(hv[2]), az);
                az = fdot2(u2h(wz[i][3]), u2h(hv[3]), az);
                an = fdot2(u2h(wn[i][0]), u2h(hv[0]), an);
                an = fdot2(u2h(wn[i][1]), u2h(hv[1]), an);
                an = fdot2(u2h(wn[i][2]), u2h(hv[2]), an);
                an = fdot2(u2h(wn[i][3]), u2h(hv[3]), an);
            }
            float r = sigmoid_f(ar + br + cr);
            float z = sigmoid_f(az + bz + cz);
            float n = tanh_f(cn + r * (an + bn));
            float hnew = (1.f - z) * n + z * h_old;
            *outp = hnew;
            outp += OSTEP;
            h_old = hnew;
            hbuf[p ^ 1][j] = (_Float16)hnew;
            __syncthreads();
            p ^= 1;
        }
        // ---------------- odd step (uses B, refills B from tt+3) ----------------
        {
            float cr = grB, cz = gzB, cn = gnB;
            int tp = (tt + 3 < t_len) ? tt + 3 : t_len - 1;
            grB = (float)gib[(size_t)tp * STEP];
            gzB = (float)gib[(size_t)tp * STEP + 256];
            gnB = (float)gib[(size_t)tp * STEP + 512];

            float ar = 0.f, az = 0.f, an = 0.f;
            const uint4v* hp = (const uint4v*)hbuf[p];
            #pragma unroll
            for (int i = 0; i < 32; ++i) {
                uint4v hv = hp[i];
                ar = fdot2(u2h(wr[i][0]), u2h(hv[0]), ar);
                ar = fdot2(u2h(wr[i][1]), u2h(hv[1]), ar);
                ar = fdot2(u2h(wr[i][2]), u2h(hv[2]), ar);
                ar = fdot2(u2h(wr[i][3]), u2h(hv[3]), ar);
                az = fdot2(u2h(wz[i][0]), u2h(hv[0]), az);
                az = fdot2(u2h(wz[i][1]), u2h(hv[1]), az);
                az = fdot2(u2h(wz[i][2]), u2h(hv[2]), az);
                az = fdot2(u2h(wz[i][3]), u2h(hv[3]), az);
                an = fdot2(u2h(wn[i][0]), u2h(hv[0]), an);
                an = fdot2(u2h(wn[i][1]), u2h(hv[1]), an);
                an = fdot2(u2h(wn[i][2]), u2h(hv[2]), an);
                an = fdot2(u2h(wn[i][3]), u2h(hv[3]), an);
            }
            float r = sigmoid_f(ar + br + cr);
            float z = sigmoid_f(az + bz + cz);
            float n = tanh_f(cn + r * (an + bn));
            float hnew = (1.f - z) * n + z * h_old;
            *outp = hnew;
            outp += OSTEP;
            h_old = hnew;
            hbuf[p ^ 1][j] = (_Float16)hnew;
            __syncthreads();
            p ^= 1;
        }
    }
    hstate[b * HDIM + j] = h_old;
}

// ---------------------------------------------------------------- host
extern "C" void kernel_launch(void* const* d_in, const int* in_sizes, int n_in,
                              void* d_out, int out_size, void* d_ws, size_t ws_size,
                              hipStream_t stream) {
    const float* x     = (const float*)d_in[0];
    const float* hx    = (const float*)d_in[1];
    const float* x2h_w = (const float*)d_in[2];
    const float* h2h_w = (const float*)d_in[3];
    const float* x2h_b = (const float*)d_in[4];
    const float* h2h_b = (const float*)d_in[5];
    float* out = (float*)d_out;

    char* ws = (char*)d_ws;
    _Float16* wx16   = (_Float16*)ws;                    // 393216 B
    _Float16* wh16   = (_Float16*)(ws + 393216);         // 393216 B
    float*    hstate = (float*)(ws + 786432);            // 65536 B
    _Float16* gi     = (_Float16*)(ws + 851968);

    size_t gi_cap_elems = (ws_size > 851968) ? (ws_size - 851968) / 2 : 0;
    int CT = T_SEQ;
    while ((size_t)CT * BATCH * G3 > gi_cap_elems && CT > 64) CT >>= 1;

    cvt_init<<<768, 256, 0, stream>>>(x2h_w, h2h_w, hx, wx16, wh16, hstate,
                                      out + (size_t)T_SEQ * BATCH * HDIM);

    for (int t0 = 0; t0 < T_SEQ; t0 += CT) {
        int rows = CT * BATCH;
        gi_gemm<<<rows / 256, 256, 0, stream>>>(x, wx16, x2h_b, gi, t0 * BATCH);
        gru_rec<<<BATCH, 256, 0, stream>>>(gi, wh16, h2h_b, hx, hstate, out, t0, CT);
    }
}

// Round 3
// 2499.632 us; speedup vs baseline: 3.3337x; 3.3337x over previous
//
#include <hip/hip_runtime.h>
#include <hip/hip_fp16.h>

// GRU: T=2048, B=64, I=H=256.  out = ([T,B,H] f32, initial hx)
//
//  1) cvt_init: f32->f16 weight copies into ws, h_state := hx, write hx tail of d_out.
//  2) gi_gemm:  gi = x @ x2h_w^T + x2h_b via f16 MFMA, stored f16 in ws (parallel over T).
//  3) gru_rec:  64 WGs (one per batch element) x 512 threads, K-SPLIT BY 2:
//               thread (half, j) owns the K-slice [half*128, half*128+128) of h2h_w rows
//               {j, j+256, j+512} = 48 uint4 = 192 arch VGPRs (fits the 256 arch cap;
//               R2's 384-reg attempt spilled to scratch). Per step: 192 v_dot2_f32_f16
//               per thread on the LDS-broadcast h half, 3-float LDS partial exchange,
//               gates in-thread on the low half, 2 barriers/step, gi prefetched 2 deep.

typedef _Float16 half2v __attribute__((ext_vector_type(2)));
typedef _Float16 half8  __attribute__((ext_vector_type(8)));
typedef float    f32x4  __attribute__((ext_vector_type(4)));
typedef unsigned int uint4v __attribute__((ext_vector_type(4)));

#define T_SEQ 2048
#define BATCH 64
#define HDIM  256
#define G3    768   // 3*H

__device__ __forceinline__ half2v u2h(unsigned int u) {
    union { unsigned int u; half2v h; } c; c.u = u; return c.h;
}

__device__ __forceinline__ float fdot2(half2v a, half2v b, float c) {
#if __has_builtin(__builtin_amdgcn_fdot2)
    return __builtin_amdgcn_fdot2(a, b, c, false);
#else
    return c + (float)a[0] * (float)b[0] + (float)a[1] * (float)b[1];
#endif
}

__device__ __forceinline__ float sigmoid_f(float x) {
    return 1.f / (1.f + __expf(-x));
}
__device__ __forceinline__ float tanh_f(float x) {
    float e = __expf(2.f * x);
    return 1.f - 2.f / (e + 1.f);
}

// ---------------------------------------------------------------- cvt_init
__global__ void cvt_init(const float* __restrict__ x2h_w, const float* __restrict__ h2h_w,
                         const float* __restrict__ hx,
                         _Float16* __restrict__ wx16, _Float16* __restrict__ wh16,
                         float* __restrict__ hstate, float* __restrict__ out_tail) {
    int i = blockIdx.x * 256 + threadIdx.x;
    if (i < G3 * HDIM) {
        wx16[i] = (_Float16)x2h_w[i];
        wh16[i] = (_Float16)h2h_w[i];
    }
    if (i < BATCH * HDIM) {
        float v = hx[i];
        hstate[i] = v;
        out_tail[i] = v;   // second output = INITIAL hx
    }
}

// ---------------------------------------------------------------- gi_gemm
// mfma_f32_16x16x32_f16: A lane holds A[row=l&15, k=(l>>4)*8+i];
// B lane holds B[k=(l>>4)*8+i, col=l&15]; D lane holds C[row=(l>>4)*4+r, col=l&15].
__global__ __launch_bounds__(256) void gi_gemm(const float* __restrict__ x,
                                               const _Float16* __restrict__ wx,
                                               const float* __restrict__ bx,
                                               _Float16* __restrict__ gi,
                                               int row_base) {
    const int lane  = threadIdx.x & 63;
    const int wave  = threadIdx.x >> 6;
    const int l15   = lane & 15;
    const int kslot = lane >> 4;               // 0..3
    const int row0  = row_base + blockIdx.x * 256 + wave * 64;

    half8 a[4][8];
    #pragma unroll
    for (int s = 0; s < 4; ++s) {
        const float* xr = x + (size_t)(row0 + s * 16 + l15) * HDIM + kslot * 8;
        #pragma unroll
        for (int kt = 0; kt < 8; ++kt) {
            float4 lo = *(const float4*)(xr + kt * 32);
            float4 hi = *(const float4*)(xr + kt * 32 + 4);
            half8 v;
            v[0] = (_Float16)lo.x; v[1] = (_Float16)lo.y; v[2] = (_Float16)lo.z; v[3] = (_Float16)lo.w;
            v[4] = (_Float16)hi.x; v[5] = (_Float16)hi.y; v[6] = (_Float16)hi.z; v[7] = (_Float16)hi.w;
            a[s][kt] = v;
        }
    }

    for (int nt = 0; nt < 48; ++nt) {
        half8 b[8];
        const _Float16* wr = wx + (size_t)(nt * 16 + l15) * HDIM + kslot * 8;
        #pragma unroll
        for (int kt = 0; kt < 8; ++kt) b[kt] = *(const half8*)(wr + kt * 32);
        const int   col  = nt * 16 + l15;
        const float bias = bx[col];
        #pragma unroll
        for (int s = 0; s < 4; ++s) {
            f32x4 acc = {0.f, 0.f, 0.f, 0.f};
            #pragma unroll
            for (int kt = 0; kt < 8; ++kt)
                acc = __builtin_amdgcn_mfma_f32_16x16x32_f16(a[s][kt], b[kt], acc, 0, 0, 0);
            #pragma unroll
            for (int r = 0; r < 4; ++r) {
                int rowl = (row0 - row_base) + s * 16 + kslot * 4 + r;
                gi[(size_t)rowl * G3 + col] = (_Float16)(acc[r] + bias);
            }
        }
    }
}

// ---------------------------------------------------------------- gru_rec
// 64 WGs x 512 threads. K-split-2: thread (half=tid>>8, j=tid&255) owns the
// half-K slices of h2h_w rows j / j+256 / j+512 -> 192 register-resident VGPRs.
__global__ __launch_bounds__(512, 2) void gru_rec(const _Float16* __restrict__ gi,
                                                  const _Float16* __restrict__ wh,
                                                  const float* __restrict__ bh,
                                                  const float* __restrict__ hx,
                                                  float* __restrict__ hstate,
                                                  float* __restrict__ out,
                                                  int t_start, int t_len) {
    __shared__ __align__(16) _Float16 hbuf[2][HDIM];
    __shared__ float psum[3][HDIM];

    const int tid  = threadIdx.x;
    const int half = tid >> 8;            // 0: K in [0,128), 1: K in [128,256)
    const int j    = tid & 255;
    const int b    = blockIdx.x;

    // 3 half-rows -> 48 x uint4v = 192 VGPRs, pinned (fits 256-arch cap)
    uint4v wr[16], wz[16], wn[16];
    {
        const uint4v* pr = (const uint4v*)(wh + (size_t)j * HDIM + half * 128);
        const uint4v* pz = (const uint4v*)(wh + (size_t)(j + 256) * HDIM + half * 128);
        const uint4v* pn = (const uint4v*)(wh + (size_t)(j + 512) * HDIM + half * 128);
        #pragma unroll
        for (int i = 0; i < 16; ++i) { wr[i] = pr[i]; wz[i] = pz[i]; wn[i] = pn[i]; }
    }
    #pragma unroll
    for (int i = 0; i < 16; ++i)
        asm volatile("" : "+v"(wr[i]), "+v"(wz[i]), "+v"(wn[i]));

    const float br = bh[j];
    const float bz = bh[j + 256];
    const float bn = bh[j + 512];

    float h_old = 0.f;
    if (half == 0) {
        h_old = (t_start == 0) ? hx[b * HDIM + j] : hstate[b * HDIM + j];
        hbuf[0][j] = (_Float16)h_old;
    }
    __syncthreads();

    const _Float16* gib = gi + (size_t)b * G3 + j;
    const size_t STEP = (size_t)BATCH * G3;

    // 2-deep gi prefetch (low half only): A = step tt, B = step tt+1
    float grA = 0.f, gzA = 0.f, gnA = 0.f, grB = 0.f, gzB = 0.f, gnB = 0.f;
    if (half == 0) {
        grA = (float)gib[0];
        gzA = (float)gib[256];
        gnA = (float)gib[512];
        grB = (float)gib[STEP];
        gzB = (float)gib[STEP + 256];
        gnB = (float)gib[STEP + 512];
    }

    int p = 0;
    float* outp = out + ((size_t)t_start * BATCH + b) * HDIM + j;
    const size_t OSTEP = (size_t)BATCH * HDIM;

    for (int tt = 0; tt < t_len; tt += 2) {
        // ---------------- even step (uses A, refills A from tt+2) ----------------
        {
            float cr = grA, cz = gzA, cn = gnA;
            if (half == 0) {
                int tp = (tt + 2 < t_len) ? tt + 2 : t_len - 1;
                grA = (float)gib[(size_t)tp * STEP];
                gzA = (float)gib[(size_t)tp * STEP + 256];
                gnA = (float)gib[(size_t)tp * STEP + 512];
            }
            float ar = 0.f, az = 0.f, an = 0.f;
            const uint4v* hp = (const uint4v*)&hbuf[p][half * 128];
            #pragma unroll
            for (int i = 0; i < 16; ++i) {
                uint4v hv = hp[i];
                ar = fdot2(u2h(wr[i][0]), u2h(hv[0]), ar);
                ar = fdot2(u2h(wr[i][1]), u2h(hv[1]), ar);
                ar = fdot2(u2h(wr[i][2]), u2h(hv[2]), ar);
                ar = fdot2(u2h(wr[i][3]), u2h(hv[3]), ar);
                az = fdot2(u2h(wz[i][0]), u2h(hv[0]), az);
                az = fdot2(u2h(wz[i][1]), u2h(hv[1]), az);
                az = fdot2(u2h(wz[i][2]), u2h(hv[2]), az);
                az = fdot2(u2h(wz[i][3]), u2h(hv[3]), az);
                an = fdot2(u2h(wn[i][0]), u2h(hv[0]), an);
                an = fdot2(u2h(wn[i][1]), u2h(hv[1]), an);
                an = fdot2(u2h(wn[i][2]), u2h(hv[2]), an);
                an = fdot2(u2h(wn[i][3]), u2h(hv[3]), an);
            }
            if (half) { psum[0][j] = ar; psum[1][j] = az; psum[2][j] = an; }
            __syncthreads();
            if (!half) {
                float r = sigmoid_f(ar + psum[0][j] + br + cr);
                float z = sigmoid_f(az + psum[1][j] + bz + cz);
                float n = tanh_f(cn + r * (an + psum[2][j] + bn));
                float hnew = (1.f - z) * n + z * h_old;
                *outp = hnew;
                outp += OSTEP;
                h_old = hnew;
                hbuf[p ^ 1][j] = (_Float16)hnew;
            }
            __syncthreads();
            p ^= 1;
        }
        // ---------------- odd step (uses B, refills B from tt+3) ----------------
        {
            float cr = grB, cz = gzB, cn = gnB;
            if (half == 0) {
                int tp = (tt + 3 < t_len) ? tt + 3 : t_len - 1;
                grB = (float)gib[(size_t)tp * STEP];
                gzB = (float)gib[(size_t)tp * STEP + 256];
                gnB = (float)gib[(size_t)tp * STEP + 512];
            }
            float ar = 0.f, az = 0.f, an = 0.f;
            const uint4v* hp = (const uint4v*)&hbuf[p][half * 128];
            #pragma unroll
            for (int i = 0; i < 16; ++i) {
                uint4v hv = hp[i];
                ar = fdot2(u2h(wr[i][0]), u2h(hv[0]), ar);
                ar = fdot2(u2h(wr[i][1]), u2h(hv[1]), ar);
                ar = fdot2(u2h(wr[i][2]), u2h(hv[2]), ar);
                ar = fdot2(u2h(wr[i][3]), u2h(hv[3]), ar);
                az = fdot2(u2h(wz[i][0]), u2h(hv[0]), az);
                az = fdot2(u2h(wz[i][1]), u2h(hv[1]), az);
                az = fdot2(u2h(wz[i][2]), u2h(hv[2]), az);
                az = fdot2(u2h(wz[i][3]), u2h(hv[3]), az);
                an = fdot2(u2h(wn[i][0]), u2h(hv[0]), an);
                an = fdot2(u2h(wn[i][1]), u2h(hv[1]), an);
                an = fdot2(u2h(wn[i][2]), u2h(hv[2]), an);
                an = fdot2(u2h(wn[i][3]), u2h(hv[3]), an);
            }
            if (half) { psum[0][j] = ar; psum[1][j] = az; psum[2][j] = an; }
            __syncthreads();
            if (!half) {
                float r = sigmoid_f(ar + psum[0][j] + br + cr);
                float z = sigmoid_f(az + psum[1][j] + bz + cz);
                float n = tanh_f(cn + r * (an + psum[2][j] + bn));
                float hnew = (1.f - z) * n + z * h_old;
                *outp = hnew;
                outp += OSTEP;
                h_old = hnew;
                hbuf[p ^ 1][j] = (_Float16)hnew;
            }
            __syncthreads();
            p ^= 1;
        }
    }
    if (!half) hstate[b * HDIM + j] = h_old;
}

// ---------------------------------------------------------------- host
extern "C" void kernel_launch(void* const* d_in, const int* in_sizes, int n_in,
                              void* d_out, int out_size, void* d_ws, size_t ws_size,
                              hipStream_t stream) {
    const float* x     = (const float*)d_in[0];
    const float* hx    = (const float*)d_in[1];
    const float* x2h_w = (const float*)d_in[2];
    const float* h2h_w = (const float*)d_in[3];
    const float* x2h_b = (const float*)d_in[4];
    const float* h2h_b = (const float*)d_in[5];
    float* out = (float*)d_out;

    char* ws = (char*)d_ws;
    _Float16* wx16   = (_Float16*)ws;                    // 393216 B
    _Float16* wh16   = (_Float16*)(ws + 393216);         // 393216 B
    float*    hstate = (float*)(ws + 786432);            // 65536 B
    _Float16* gi     = (_Float16*)(ws + 851968);

    size_t gi_cap_elems = (ws_size > 851968) ? (ws_size - 851968) / 2 : 0;
    int CT = T_SEQ;
    while ((size_t)CT * BATCH * G3 > gi_cap_elems && CT > 64) CT >>= 1;

    cvt_init<<<768, 256, 0, stream>>>(x2h_w, h2h_w, hx, wx16, wh16, hstate,
                                      out + (size_t)T_SEQ * BATCH * HDIM);

    for (int t0 = 0; t0 < T_SEQ; t0 += CT) {
        int rows = CT * BATCH;
        gi_gemm<<<rows / 256, 256, 0, stream>>>(x, wx16, x2h_b, gi, t0 * BATCH);
        gru_rec<<<BATCH, 512, 0, stream>>>(gi, wh16, h2h_b, hx, hstate, out, t0, CT);
    }
}